// Round 8
// baseline (177.721 us; speedup 1.0000x reference)
//
#include <hip/hip_runtime.h>

// LATTE forward, fully reduced:
//   R2: message = v[dst] => segment-softmax weights sum to 1 => h_m = v * (deg_m>0).
//   R6: beta-softmax is over HEADS; active relations share logits; per-row scalar cnt
//       cancels in LayerNorm => edges/flags ALL DEAD.
//   out = ReLU(LN(v * sm(v)) * gamma + beta),  v = feat@Wr + br,
//   sm[n,h] = softmax_h(lrelu(v_n.rl_h + v_n.rr_h)).
// R8: R7 was 1 block/CU (156 regs/wave => 3 waves/SIMD; 512-thr blocks need 4) => 2
//     serialized generations. Now: 256-thr blocks, __launch_bounds__(256,3), B in 4x32KB
//     chunks => 3 blocks/CU, grid 782 = one generation. A stays register-preloaded (R7).

#define NN 50000
#define NT 3125    // 50000/16 row-tiles
#define NB 782     // ceil(NT/4): 4 wave-tiles per block
#define NEG 0.2f
#define EPSV 1e-5f

typedef __attribute__((ext_vector_type(8))) short bf16x8;
typedef __attribute__((ext_vector_type(4))) float f32x4;

#define LDS_FENCE() asm volatile("s_waitcnt lgkmcnt(0)" ::: "memory")

__device__ __forceinline__ short f2bf(float f) {   // RNE fp32->bf16
    unsigned u = __float_as_uint(f);
    u += 0x7fff + ((u >> 16) & 1);
    return (short)(u >> 16);
}

__device__ __forceinline__ void ld_g2l_16(void* lds, const void* g) {
    __builtin_amdgcn_global_load_lds(
        (const __attribute__((address_space(1))) unsigned int*)g,
        (__attribute__((address_space(3))) unsigned int*)lds, 16, 0, 0);
}

// 8 blocks: Wt[n][k] = bf16(Wr[k][n]) via LDS (coalesced reads, 64B/thread writes).
__global__ __launch_bounds__(256) void prep_kernel(
    const float* __restrict__ Wr, unsigned short* __restrict__ Wt)
{
    __shared__ float ws[32 * 256];   // 32 KB
    int t = threadIdx.x;
    int kb = blockIdx.x * 32;
#pragma unroll
    for (int i = 0; i < 32; ++i)
        ws[i * 256 + t] = Wr[(size_t)(kb + i) * 256 + t];
    __syncthreads();
#pragma unroll
    for (int c = 0; c < 4; ++c) {
        bf16x8 o;
#pragma unroll
        for (int j = 0; j < 8; ++j)
            o[j] = f2bf(ws[(c * 8 + j) * 256 + t]);
        *reinterpret_cast<bf16x8*>(&Wt[(size_t)t * 256 + kb + c * 8]) = o;
    }
}

// 256 threads = 4 waves; wave's tile = blockIdx*4+wave = 16 rows x 256 cols.
// mfma 16x16x32 bf16: A[m=lane&15][k=quad*8+j], B[k][n=lane&15], C row=quad*4+reg col=lane&15.
// LDS: one 32KB K-chunk of B^T (XOR-swizzled); reused post-compute as 4x8KB store scratch.
__global__ __launch_bounds__(256, 3) void fused_kernel(
    const float* __restrict__ feat, const unsigned short* __restrict__ Wt,
    const float* __restrict__ br, const float* __restrict__ rl,
    const float* __restrict__ rr, const float* __restrict__ gamma,
    const float* __restrict__ beta, float* __restrict__ out)
{
    __shared__ __align__(16) char smem[32768];
    unsigned short* Bs = (unsigned short*)smem;
    const int t = threadIdx.x;
    const int wave = t >> 6, lane = t & 63;
    const int cl = lane & 15, quad = lane >> 4;
    const int tile = blockIdx.x * 4 + wave;
    const bool act = tile < NT;
    const int row0 = tile * 16;

    f32x4 acc[16];
#pragma unroll
    for (int i = 0; i < 16; ++i) acc[i] = (f32x4){0.f, 0.f, 0.f, 0.f};

    // lane's ENTIRE A fragment (K=256): loaded before any barrier, converted to bf16.
    // afr[kk8] covers k = kk8*32 + quad*8 .. +7 (mfma A-operand layout).
    bf16x8 afr[8];
    if (act) {
        const float* arow = feat + (size_t)(row0 + cl) * 256;
#pragma unroll
        for (int kk8 = 0; kk8 < 8; ++kk8) {
            int k0 = kk8 * 32 + quad * 8;
            float4 a0 = *reinterpret_cast<const float4*>(arow + k0);
            float4 a1 = *reinterpret_cast<const float4*>(arow + k0 + 4);
            afr[kk8][0] = f2bf(a0.x); afr[kk8][1] = f2bf(a0.y);
            afr[kk8][2] = f2bf(a0.z); afr[kk8][3] = f2bf(a0.w);
            afr[kk8][4] = f2bf(a1.x); afr[kk8][5] = f2bf(a1.y);
            afr[kk8][6] = f2bf(a1.z); afr[kk8][7] = f2bf(a1.w);
        }
    }

#pragma unroll
    for (int chunk = 0; chunk < 4; ++chunk) {
        if (chunk) __syncthreads();        // protect LDS before overwrite
        // B-chunk DMA: 32KB = 2048 x 16B slots; slot s: n=s>>3, k-group (s&7)^(n&7)
#pragma unroll
        for (int c = 0; c < 8; ++c) {
            int s = c * 256 + t;
            int n = s >> 3;
            int ksg = (s & 7) ^ (n & 7);
            ld_g2l_16(&Bs[(size_t)s * 8], Wt + n * 256 + chunk * 64 + ksg * 8);
        }
        __syncthreads();                   // drains vmcnt for the DMA
        if (act) {
#pragma unroll
            for (int kk = 0; kk < 2; ++kk) {
                bf16x8 af = afr[chunk * 2 + kk];
                int ks = kk * 4 + quad;    // k-group within chunk (0..7)
#pragma unroll
                for (int ct = 0; ct < 16; ++ct) {
                    int n = ct * 16 + cl;
                    bf16x8 bf = *reinterpret_cast<const bf16x8*>(
                        &Bs[(size_t)(n * 8 + (ks ^ (n & 7))) * 8]);
                    acc[ct] = __builtin_amdgcn_mfma_f32_16x16x32_bf16(af, bf, acc[ct], 0, 0, 0);
                }
            }
        }
    }
    __syncthreads();   // all waves done reading Bs; LDS becomes per-wave scratch
    if (!act) return;

    // ---- fused epilogue (per wave: 16 rows x 256 cols, C-layout) ----
#pragma unroll
    for (int ct = 0; ct < 16; ++ct) {
        float bc = br[ct * 16 + cl];
#pragma unroll
        for (int r = 0; r < 4; ++r) acc[ct][r] += bc;
    }
    // per-head dots -> logits z[h][r]  (quad owns rows quad*4+r)
    float z[4][4];
#pragma unroll
    for (int h = 0; h < 4; ++h) {
        float sl[4] = {0, 0, 0, 0}, sr[4] = {0, 0, 0, 0};
#pragma unroll
        for (int j = 0; j < 4; ++j) {
            int ct = h * 4 + j;
            float rlc = rl[ct * 16 + cl], rrc = rr[ct * 16 + cl];
#pragma unroll
            for (int r = 0; r < 4; ++r) {
                sl[r] += acc[ct][r] * rlc;
                sr[r] += acc[ct][r] * rrc;
            }
        }
#pragma unroll
        for (int off = 1; off < 16; off <<= 1)
#pragma unroll
            for (int r = 0; r < 4; ++r) {
                sl[r] += __shfl_xor(sl[r], off, 64);
                sr[r] += __shfl_xor(sr[r], off, 64);
            }
#pragma unroll
        for (int r = 0; r < 4; ++r) {
            float x = sl[r] + sr[r];
            z[h][r] = x > 0.f ? x : NEG * x;
        }
    }
    // softmax over heads (scalar cnt cancels in LN — no graph terms)
    float gg[4][4];   // [h][r]
#pragma unroll
    for (int r = 0; r < 4; ++r) {
        float mx = fmaxf(fmaxf(z[0][r], z[1][r]), fmaxf(z[2][r], z[3][r]));
        float e0 = __expf(z[0][r] - mx), e1 = __expf(z[1][r] - mx);
        float e2 = __expf(z[2][r] - mx), e3 = __expf(z[3][r] - mx);
        float inv = 1.f / (e0 + e1 + e2 + e3);
        gg[0][r] = e0 * inv; gg[1][r] = e1 * inv;
        gg[2][r] = e2 * inv; gg[3][r] = e3 * inv;
    }
    // gate + LN stats
    float s[4] = {0, 0, 0, 0}, s2[4] = {0, 0, 0, 0};
#pragma unroll
    for (int ct = 0; ct < 16; ++ct) {
        int h = ct >> 2;
#pragma unroll
        for (int r = 0; r < 4; ++r) {
            float o = acc[ct][r] * gg[h][r];
            acc[ct][r] = o;
            s[r] += o;
            s2[r] += o * o;
        }
    }
#pragma unroll
    for (int off = 1; off < 16; off <<= 1)
#pragma unroll
        for (int r = 0; r < 4; ++r) {
            s[r] += __shfl_xor(s[r], off, 64);
            s2[r] += __shfl_xor(s2[r], off, 64);
        }
    float mu[4], rstd[4];
#pragma unroll
    for (int r = 0; r < 4; ++r) {
        mu[r] = s[r] * (1.f / 256.f);
        float var = s2[r] * (1.f / 256.f) - mu[r] * mu[r];
        rstd[r] = rsqrtf(var + EPSV);
    }
    // coalesced store: LN+ReLU folded into per-wave 8KB LDS transpose, 2 passes x 8 rows
    float* tb = reinterpret_cast<float*>(smem) + wave * 2048;
#pragma unroll
    for (int p = 0; p < 2; ++p) {
#pragma unroll
        for (int ct = 0; ct < 16; ++ct) {
            float ga = gamma[ct * 16 + cl], be = beta[ct * 16 + cl];
            float v0 = fmaxf((acc[ct][2 * p + 0] - mu[2 * p + 0]) * rstd[2 * p + 0] * ga + be, 0.f);
            float v1 = fmaxf((acc[ct][2 * p + 1] - mu[2 * p + 1]) * rstd[2 * p + 1] * ga + be, 0.f);
            tb[(quad * 2 + 0) * 256 + ct * 16 + cl] = v0;
            tb[(quad * 2 + 1) * 256 + ct * 16 + cl] = v1;
        }
        LDS_FENCE();   // same-wave cross-lane RAW on LDS
#pragma unroll
        for (int sl8 = 0; sl8 < 8; ++sl8) {
            int trow = (sl8 >> 1) * 4 + 2 * p + (sl8 & 1);
            float4 v4 = *reinterpret_cast<const float4*>(&tb[sl8 * 256 + lane * 4]);
            *reinterpret_cast<float4*>(&out[(size_t)(row0 + trow) * 256 + lane * 4]) = v4;
        }
        LDS_FENCE();   // WAR: reads complete before next pass overwrites
    }
}

extern "C" void kernel_launch(void* const* d_in, const int* in_sizes, int n_in,
                              void* d_out, int out_size, void* d_ws, size_t ws_size,
                              hipStream_t stream) {
    const float* feat = (const float*)d_in[0];
    const float* Wr   = (const float*)d_in[3];
    const float* br   = (const float*)d_in[4];
    const float* rl   = (const float*)d_in[7];
    const float* rr   = (const float*)d_in[8];
    const float* gam  = (const float*)d_in[9];
    const float* bet  = (const float*)d_in[10];
    float* out = (float*)d_out;
    unsigned short* Wt = (unsigned short*)d_ws;   // 128 KB bf16 W^T

    prep_kernel<<<8, 256, 0, stream>>>(Wr, Wt);
    fused_kernel<<<NB, 256, 0, stream>>>(feat, Wt, br, rl, rr, gam, bet, out);
}

// Round 9
// 152.684 us; speedup vs baseline: 1.1640x; 1.1640x over previous
//
#include <hip/hip_runtime.h>

// LATTE forward, fully reduced:
//   R2: message = v[dst] => segment-softmax weights sum to 1 => h_m = v * (deg_m>0).
//   R6: beta-softmax is over HEADS; active relations share logits; per-row scalar cnt
//       cancels in LayerNorm => edges/flags ALL DEAD.
//   out = ReLU(LN(v * sm(v)) * gamma + beta),  v = feat@Wr + br,
//   sm[n,h] = softmax_h(lrelu(v_n.rl_h + v_n.rr_h)).
// R9: R7 structure (ONLY clean-traffic shape: 512 thr, 2 K-halves, (512,2)) + 2 tiles
//     per wave => each B ds_read_b128 feeds 2 MFMAs (B LDS bytes/tile halved) and grid
//     196 = one block-round (R7 ran 2 sequential rounds/CU). A loaded per K-half.

#define NN 50000
#define NT 3125    // 50000/16 row-tiles
#define NW 1568    // wave-slots = 196 blocks x 8 waves; wave does tiles ws and ws+NW
#define NBLK 196
#define NEG 0.2f
#define EPSV 1e-5f

typedef __attribute__((ext_vector_type(8))) short bf16x8;
typedef __attribute__((ext_vector_type(4))) float f32x4;

#define LDS_FENCE() asm volatile("s_waitcnt lgkmcnt(0)" ::: "memory")

__device__ __forceinline__ short f2bf(float f) {   // RNE fp32->bf16
    unsigned u = __float_as_uint(f);
    u += 0x7fff + ((u >> 16) & 1);
    return (short)(u >> 16);
}

__device__ __forceinline__ void ld_g2l_16(void* lds, const void* g) {
    __builtin_amdgcn_global_load_lds(
        (const __attribute__((address_space(1))) unsigned int*)g,
        (__attribute__((address_space(3))) unsigned int*)lds, 16, 0, 0);
}

// 8 blocks: Wt[n][k] = bf16(Wr[k][n]) via LDS (coalesced reads, 64B/thread writes).
__global__ __launch_bounds__(256) void prep_kernel(
    const float* __restrict__ Wr, unsigned short* __restrict__ Wt)
{
    __shared__ float ws[32 * 256];   // 32 KB
    int t = threadIdx.x;
    int kb = blockIdx.x * 32;
#pragma unroll
    for (int i = 0; i < 32; ++i)
        ws[i * 256 + t] = Wr[(size_t)(kb + i) * 256 + t];
    __syncthreads();
#pragma unroll
    for (int c = 0; c < 4; ++c) {
        bf16x8 o;
#pragma unroll
        for (int j = 0; j < 8; ++j)
            o[j] = f2bf(ws[(c * 8 + j) * 256 + t]);
        *reinterpret_cast<bf16x8*>(&Wt[(size_t)t * 256 + kb + c * 8]) = o;
    }
}

// Per-tile epilogue on the MFMA C-layout (row=quad*4+r, col=ct*16+cl). Uses the wave's
// private 8KB LDS scratch tb for the coalesced store-transpose.
__device__ __forceinline__ void epilogue(
    f32x4* acc, int row0, int lane, int cl, int quad,
    const float* __restrict__ br, const float* __restrict__ rl,
    const float* __restrict__ rr, const float* __restrict__ gamma,
    const float* __restrict__ beta, float* tb, float* __restrict__ out)
{
#pragma unroll
    for (int ct = 0; ct < 16; ++ct) {
        float bc = br[ct * 16 + cl];
#pragma unroll
        for (int r = 0; r < 4; ++r) acc[ct][r] += bc;
    }
    float z[4][4];
#pragma unroll
    for (int h = 0; h < 4; ++h) {
        float sl[4] = {0, 0, 0, 0}, sr[4] = {0, 0, 0, 0};
#pragma unroll
        for (int j = 0; j < 4; ++j) {
            int ct = h * 4 + j;
            float rlc = rl[ct * 16 + cl], rrc = rr[ct * 16 + cl];
#pragma unroll
            for (int r = 0; r < 4; ++r) {
                sl[r] += acc[ct][r] * rlc;
                sr[r] += acc[ct][r] * rrc;
            }
        }
#pragma unroll
        for (int off = 1; off < 16; off <<= 1)
#pragma unroll
            for (int r = 0; r < 4; ++r) {
                sl[r] += __shfl_xor(sl[r], off, 64);
                sr[r] += __shfl_xor(sr[r], off, 64);
            }
#pragma unroll
        for (int r = 0; r < 4; ++r) {
            float x = sl[r] + sr[r];
            z[h][r] = x > 0.f ? x : NEG * x;
        }
    }
    float gg[4][4];
#pragma unroll
    for (int r = 0; r < 4; ++r) {
        float mx = fmaxf(fmaxf(z[0][r], z[1][r]), fmaxf(z[2][r], z[3][r]));
        float e0 = __expf(z[0][r] - mx), e1 = __expf(z[1][r] - mx);
        float e2 = __expf(z[2][r] - mx), e3 = __expf(z[3][r] - mx);
        float inv = 1.f / (e0 + e1 + e2 + e3);
        gg[0][r] = e0 * inv; gg[1][r] = e1 * inv;
        gg[2][r] = e2 * inv; gg[3][r] = e3 * inv;
    }
    float s[4] = {0, 0, 0, 0}, s2[4] = {0, 0, 0, 0};
#pragma unroll
    for (int ct = 0; ct < 16; ++ct) {
        int h = ct >> 2;
#pragma unroll
        for (int r = 0; r < 4; ++r) {
            float o = acc[ct][r] * gg[h][r];
            acc[ct][r] = o;
            s[r] += o;
            s2[r] += o * o;
        }
    }
#pragma unroll
    for (int off = 1; off < 16; off <<= 1)
#pragma unroll
        for (int r = 0; r < 4; ++r) {
            s[r] += __shfl_xor(s[r], off, 64);
            s2[r] += __shfl_xor(s2[r], off, 64);
        }
    float mu[4], rstd[4];
#pragma unroll
    for (int r = 0; r < 4; ++r) {
        mu[r] = s[r] * (1.f / 256.f);
        float var = s2[r] * (1.f / 256.f) - mu[r] * mu[r];
        rstd[r] = rsqrtf(var + EPSV);
    }
#pragma unroll
    for (int p = 0; p < 2; ++p) {
#pragma unroll
        for (int ct = 0; ct < 16; ++ct) {
            float ga = gamma[ct * 16 + cl], be = beta[ct * 16 + cl];
            float v0 = fmaxf((acc[ct][2 * p + 0] - mu[2 * p + 0]) * rstd[2 * p + 0] * ga + be, 0.f);
            float v1 = fmaxf((acc[ct][2 * p + 1] - mu[2 * p + 1]) * rstd[2 * p + 1] * ga + be, 0.f);
            tb[(quad * 2 + 0) * 256 + ct * 16 + cl] = v0;
            tb[(quad * 2 + 1) * 256 + ct * 16 + cl] = v1;
        }
        LDS_FENCE();   // same-wave cross-lane RAW on LDS
#pragma unroll
        for (int sl8 = 0; sl8 < 8; ++sl8) {
            int trow = (sl8 >> 1) * 4 + 2 * p + (sl8 & 1);
            float4 v4 = *reinterpret_cast<const float4*>(&tb[sl8 * 256 + lane * 4]);
            *reinterpret_cast<float4*>(&out[(size_t)(row0 + trow) * 256 + lane * 4]) = v4;
        }
        LDS_FENCE();   // WAR before next pass / next tile overwrites
    }
}

// 512 threads = 8 waves; wave computes 2 tiles (ws, ws+1568) sharing every B fragment.
// mfma 16x16x32 bf16: A[m=lane&15][k=quad*8+j], B[k][n=lane&15], C row=quad*4+reg col=lane&15.
__global__ __launch_bounds__(512, 2) void fused_kernel(
    const float* __restrict__ feat, const unsigned short* __restrict__ Wt,
    const float* __restrict__ br, const float* __restrict__ rl,
    const float* __restrict__ rr, const float* __restrict__ gamma,
    const float* __restrict__ beta, float* __restrict__ out)
{
    // phase 1: one K-half of B^T, XOR-swizzled (slot s: n=s>>4, ks=(s&15)^(n&15))
    // phase 2 (after compute): per-wave 8KB float scratch for the store transpose
    __shared__ __align__(16) char smem[65536];
    unsigned short* Bs = (unsigned short*)smem;
    const int t = threadIdx.x;
    const int wave = t >> 6, lane = t & 63;
    const int cl = lane & 15, quad = lane >> 4;
    const int ws = blockIdx.x * 8 + wave;   // [0,1568), always active
    const int t1 = ws + NW;
    const bool act1 = t1 < NT;
    const int r0 = ws * 16;
    const int r1 = (act1 ? t1 : 0) * 16;

    f32x4 acc0[16], acc1[16];
#pragma unroll
    for (int i = 0; i < 16; ++i) {
        acc0[i] = (f32x4){0.f, 0.f, 0.f, 0.f};
        acc1[i] = (f32x4){0.f, 0.f, 0.f, 0.f};
    }
    const float* arow0 = feat + (size_t)(r0 + cl) * 256;
    const float* arow1 = feat + (size_t)(r1 + cl) * 256;

#pragma unroll
    for (int half = 0; half < 2; ++half) {
        if (half) __syncthreads();         // protect LDS before overwrite
#pragma unroll
        for (int c = 0; c < 8; ++c) {      // stage 64KB B-half: 8 slots/thread
            int s = c * 512 + t;
            int n = s >> 4;
            int ks = (s & 15) ^ (n & 15);
            ld_g2l_16(&Bs[(size_t)(c * 512 + wave * 64) * 8],
                      Wt + n * 256 + half * 128 + ks * 8);
        }
        // A fragments for this K-half, both tiles (global, wave-private, overlaps DMA)
        bf16x8 af0[4], af1[4];
#pragma unroll
        for (int kk = 0; kk < 4; ++kk) {
            int k0 = half * 128 + kk * 32 + quad * 8;
            float4 a0 = *reinterpret_cast<const float4*>(arow0 + k0);
            float4 a1 = *reinterpret_cast<const float4*>(arow0 + k0 + 4);
            float4 b0 = *reinterpret_cast<const float4*>(arow1 + k0);
            float4 b1 = *reinterpret_cast<const float4*>(arow1 + k0 + 4);
            af0[kk][0] = f2bf(a0.x); af0[kk][1] = f2bf(a0.y);
            af0[kk][2] = f2bf(a0.z); af0[kk][3] = f2bf(a0.w);
            af0[kk][4] = f2bf(a1.x); af0[kk][5] = f2bf(a1.y);
            af0[kk][6] = f2bf(a1.z); af0[kk][7] = f2bf(a1.w);
            af1[kk][0] = f2bf(b0.x); af1[kk][1] = f2bf(b0.y);
            af1[kk][2] = f2bf(b0.z); af1[kk][3] = f2bf(b0.w);
            af1[kk][4] = f2bf(b1.x); af1[kk][5] = f2bf(b1.y);
            af1[kk][6] = f2bf(b1.z); af1[kk][7] = f2bf(b1.w);
        }
        __syncthreads();                   // drains vmcnt for the DMA
#pragma unroll
        for (int kk = 0; kk < 4; ++kk) {
            int ks = kk * 4 + quad;
#pragma unroll
            for (int ct = 0; ct < 16; ++ct) {
                int n = ct * 16 + cl;
                bf16x8 bf = *reinterpret_cast<const bf16x8*>(
                    &Bs[(size_t)(n * 16 + (ks ^ (n & 15))) * 8]);
                acc0[ct] = __builtin_amdgcn_mfma_f32_16x16x32_bf16(af0[kk], bf, acc0[ct], 0, 0, 0);
                acc1[ct] = __builtin_amdgcn_mfma_f32_16x16x32_bf16(af1[kk], bf, acc1[ct], 0, 0, 0);
            }
        }
    }
    __syncthreads();   // all waves done reading Bs; LDS becomes per-wave scratch

    float* tb = reinterpret_cast<float*>(smem) + wave * 2048;
    epilogue(acc0, r0, lane, cl, quad, br, rl, rr, gamma, beta, tb, out);
    if (act1)
        epilogue(acc1, r1, lane, cl, quad, br, rl, rr, gamma, beta, tb, out);
}

extern "C" void kernel_launch(void* const* d_in, const int* in_sizes, int n_in,
                              void* d_out, int out_size, void* d_ws, size_t ws_size,
                              hipStream_t stream) {
    const float* feat = (const float*)d_in[0];
    const float* Wr   = (const float*)d_in[3];
    const float* br   = (const float*)d_in[4];
    const float* rl   = (const float*)d_in[7];
    const float* rr   = (const float*)d_in[8];
    const float* gam  = (const float*)d_in[9];
    const float* bet  = (const float*)d_in[10];
    float* out = (float*)d_out;
    unsigned short* Wt = (unsigned short*)d_ws;   // 128 KB bf16 W^T

    prep_kernel<<<8, 256, 0, stream>>>(Wr, Wt);
    fused_kernel<<<NBLK, 512, 0, stream>>>(feat, Wt, br, rl, rr, gam, bet, out);
}